// Round 1
// baseline (113.664 us; speedup 1.0000x reference)
//
#include <hip/hip_runtime.h>
#include <hip/hip_fp16.h>

#define IMH 1024
#define IMW 1024
#define GD 8
#define GH 16
#define GW 16
#define NC 12
#define NZB 7     // z-pair entries zb in [0,6]; entry = {z=zb coeffs, z=zb+1 coeffs}
#define ENT 24    // halfs per (x,zb) entry (48 B, 16B-aligned)
#define ROWS 4

// R6: vectorize ALL global I/O to float4 (16 B/lane — G13 / m13 BW ceiling).
// Thread t owns pixels x = 4t..4t+3 of each row. x-cell boundaries fall at
// x%64==32 and 32%4==0, so a 4-px group never straddles a cell: fx/xo0/xo1
// are per-thread constants; only tx varies (+1/64 per pixel).
// Global VMEM per thread-row: 28 scalar insts -> 7 float4 insts.
// Trade: a wave now spans ~5 x-cells (was <=2), so the LDS entry-quad
// spread degrades to ~3-4-way conflicts on the 6 ds_read_b128/pixel —
// LDS path ~8us, still under the ~19us HBM floor, so it stays hidden.
// Structure otherwise unchanged: ONE barrier per block, all ROWS rows'
// y-lerped grids staged up-front, barrier-free compute so the compiler
// pipelines loads across rows with fine-grained vmcnt.
__global__ __launch_bounds__(256, 4) void bsa_kernel(
    const float* __restrict__ grid,
    const float* __restrict__ guide,
    const float* __restrict__ image,
    float* __restrict__ out)
{
    const int y0  = blockIdx.x * ROWS;
    const int b   = blockIdx.y;
    const int tid = threadIdx.x;

    __shared__ __align__(16) __half sH[ROWS][GW][NZB][ENT];   // 21 KB

    const float* gb = grid + (size_t)b * NC * GD * GH * GW;

    // ---- hoisted per-thread x-interp (constant across rows AND across the
    //      thread's 4 contiguous pixels)
    const int   x4  = tid << 2;
    const float gx0 = (x4 + 0.5f) * ((float)GW / IMW);
    const float fxf = floorf(gx0 - 0.5f);
    const float tx0 = gx0 - 0.5f - fxf;
    const int   fx  = (int)fxf;
    const int   xo0 = min(GW - 1, max(0, fx))     * (NZB * ENT);
    const int   xo1 = min(GW - 1, max(0, fx + 1)) * (NZB * ENT);

    // ---- stage all ROWS rows, one barrier
    {
        // 256 threads = 16x * 8z * 2 c-halves
        const int q  = tid >> 1;
        const int x  = q & (GW - 1);
        const int z  = q >> 4;             // [0,8)
        const int c0 = (tid & 1) * 6;

        // fy uniform across the 4-aligned row group (cell boundary at y%64==32)
        const float gy0 = (y0 + 0.5f) * ((float)GH / IMH);
        const int   fy  = (int)floorf(gy0 - 0.5f);
        const int   iy0 = min(GH - 1, max(0, fy));
        const int   iy1 = min(GH - 1, max(0, fy + 1));

        float v0[6], v1[6];
        #pragma unroll
        for (int c = 0; c < 6; ++c) {
            const int cc = c0 + c;
            v0[c] = gb[((cc * GD + z) * GH + iy0) * GW + x];
            v1[c] = gb[((cc * GD + z) * GH + iy1) * GW + x];
        }

        #pragma unroll
        for (int r = 0; r < ROWS; ++r) {
            const float ty = (y0 + r + 0.5f) * ((float)GH / IMH) - 0.5f - (float)fy;
            __half2 hv[3];
            #pragma unroll
            for (int d = 0; d < 3; ++d) {
                const float a = v0[2*d]   + ty * (v1[2*d]   - v0[2*d]);
                const float c = v0[2*d+1] + ty * (v1[2*d+1] - v0[2*d+1]);
                hv[d] = __halves2half2(__float2half(a), __float2half(c));
            }
            if (z < NZB) {
                __half2* dst = (__half2*)&sH[r][x][z][c0];
                dst[0] = hv[0]; dst[1] = hv[1]; dst[2] = hv[2];
            }
            if (z > 0) {
                __half2* dst = (__half2*)&sH[r][x][z - 1][NC + c0];
                dst[0] = hv[0]; dst[1] = hv[1]; dst[2] = hv[2];
            }
        }
    }
    __syncthreads();   // the ONLY barrier

    const size_t plane = (size_t)IMH * IMW;

    #pragma unroll
    for (int r = 0; r < ROWS; ++r) {
        const int y = y0 + r;
        const float* gp = guide + ((size_t)b * IMH + y) * IMW;
        const float* ip = image + ((size_t)b * 3 * IMH + y) * IMW;
        float*       op = out   + ((size_t)b * 3 * IMH + y) * IMW;
        const __half* S = &sH[r][0][0][0];

        // ---- vectorized global loads: 16 B/lane
        const float4 g4 = *(const float4*)(gp + x4);
        const float4 r4 = *(const float4*)(ip + x4);
        const float4 q4 = *(const float4*)(ip + x4 + plane);
        const float4 b4 = *(const float4*)(ip + x4 + 2 * plane);

        float4 o0, o1, o2;

        #pragma unroll
        for (int j = 0; j < 4; ++j) {
            const float gv = (&g4.x)[j];
            const float rv = (&r4.x)[j];
            const float g2 = (&q4.x)[j];
            const float bv = (&b4.x)[j];

            const float wx1 = tx0 + j * ((float)GW / IMW);
            const float wx0 = 1.0f - wx1;

            // z -> pair index zb + folded clamp weights
            const float gz  = gv * (float)GD;
            const float fzf = floorf(gz - 0.5f);
            const float tz  = gz - 0.5f - fzf;
            const int   fzi = (int)fzf;
            const int   zb  = min(NZB - 1, max(0, fzi));
            const float az  = (fzi < 0) ? 1.0f : ((fzi > NZB - 1) ? 0.0f : 1.0f - tz);
            const float bz  = (fzi < 0) ? 0.0f : ((fzi > NZB - 1) ? 1.0f : tz);

            const __half2 wa0 = __float2half2_rn(az * wx0);
            const __half2 wb0 = __float2half2_rn(bz * wx0);
            const __half2 wa1 = __float2half2_rn(az * wx1);
            const __half2 wb1 = __float2half2_rn(bz * wx1);

            const __half* e0 = S + xo0 + zb * ENT;
            const __half* e1 = S + xo1 + zb * ENT;

            __half2 A[12], B[12];
            *(uint4*)(A + 0) = *(const uint4*)(e0);
            *(uint4*)(A + 4) = *(const uint4*)(e0 + 8);
            *(uint4*)(A + 8) = *(const uint4*)(e0 + 16);
            *(uint4*)(B + 0) = *(const uint4*)(e1);
            *(uint4*)(B + 4) = *(const uint4*)(e1 + 8);
            *(uint4*)(B + 8) = *(const uint4*)(e1 + 16);

            __half2 cl[6];
            #pragma unroll
            for (int d = 0; d < 6; ++d) {
                __half2 t = __hmul2(wa0, A[d]);
                t = __hfma2(wb0, A[d + 6], t);
                t = __hfma2(wa1, B[d], t);
                t = __hfma2(wb1, B[d + 6], t);
                cl[d] = t;
            }

            float res[3];
            #pragma unroll
            for (int i = 0; i < 3; ++i) {
                const float c0f = __low2float(cl[2 * i]);
                const float c1f = __high2float(cl[2 * i]);
                const float c2f = __low2float(cl[2 * i + 1]);
                const float c3f = __high2float(cl[2 * i + 1]);
                res[i] = fmaf(c0f, rv, fmaf(c1f, g2, fmaf(c2f, bv, c3f)));
            }

            (&o0.x)[j] = res[0];
            (&o1.x)[j] = res[1];
            (&o2.x)[j] = res[2];
        }

        // ---- vectorized global stores: 16 B/lane
        *(float4*)(op + x4)             = o0;
        *(float4*)(op + x4 + plane)     = o1;
        *(float4*)(op + x4 + 2 * plane) = o2;
    }
}

extern "C" void kernel_launch(void* const* d_in, const int* in_sizes, int n_in,
                              void* d_out, int out_size, void* d_ws, size_t ws_size,
                              hipStream_t stream) {
    const float* grid  = (const float*)d_in[0];
    const float* guide = (const float*)d_in[1];
    const float* image = (const float*)d_in[2];
    float* out = (float*)d_out;

    const int B = in_sizes[1] / (IMH * IMW);   // guide is (B, H, W)
    dim3 g(IMH / ROWS, B);
    bsa_kernel<<<g, 256, 0, stream>>>(grid, guide, image, out);
}